// Round 5
// baseline (505.164 us; speedup 1.0000x reference)
//
#include <hip/hip_runtime.h>
#include <math.h>

#define CDIM 256
#define HW 3136
#define HID 1024

typedef __attribute__((ext_vector_type(4))) float f32x4;
typedef __attribute__((ext_vector_type(8))) short bf16x8;
typedef __attribute__((ext_vector_type(4))) short bf16x4;

__device__ __forceinline__ unsigned short f2bf(float f){
  unsigned int u = __float_as_uint(f);
  u += 0x7FFFu + ((u >> 16) & 1u);
  return (unsigned short)(u >> 16);
}

__device__ __forceinline__ void load_lds16(const void* g, void* l){
  __builtin_amdgcn_global_load_lds(
      (const __attribute__((address_space(1))) unsigned int*)g,
      (__attribute__((address_space(3))) unsigned int*)l, 16, 0, 0);
}

// ---------------- prep: w1t[f][c] = w1[c][f]; w2t[c][f] = w2[f][c]  (bf16)
__global__ __launch_bounds__(256) void prep_kernel(
    const float* __restrict__ w1, const float* __restrict__ w2,
    unsigned short* __restrict__ w1t, unsigned short* __restrict__ w2t){
  __shared__ unsigned short sh[64][70];
  int blk = blockIdx.x;
  const float* src; unsigned short* dst; int M, N, tm, tn;
  if (blk < 64){ src = w1; dst = w1t; M = 256;  N = 1024; tm = blk >> 4; tn = blk & 15; }
  else { blk -= 64; src = w2; dst = w2t; M = 1024; N = 256;  tm = blk >> 2; tn = blk & 3; }
  const int t = threadIdx.x;

  {
    const int r = t >> 4, c4 = t & 15;
    #pragma unroll
    for (int rr = 0; rr < 4; ++rr){
      int row = rr * 16 + r;
      f32x4 v = *(const f32x4*)(src + (long)(tm * 64 + row) * N + tn * 64 + c4 * 4);
      #pragma unroll
      for (int k = 0; k < 4; ++k) sh[row][c4 * 4 + k] = f2bf(v[k]);
    }
  }
  __syncthreads();

  {
    const int n = t >> 2, seg = t & 3;
    bf16x8 o0, o1;
    #pragma unroll
    for (int j = 0; j < 8; ++j){
      o0[j] = (short)sh[seg * 16 + j][n];
      o1[j] = (short)sh[seg * 16 + 8 + j][n];
    }
    unsigned short* dp = dst + (long)(tn * 64 + n) * M + tm * 64 + seg * 16;
    *(bf16x8*)(dp) = o0;
    *(bf16x8*)(dp + 8) = o1;
  }
}

// ---------------- fused depthwise 7x7 conv + bias + LayerNorm -> y bf16
// v6: occupancy fix. LDS 66.6KB -> 19.5KB (LN transpose chunked: 4 rounds of
// 14 positions, tile[256][15]); conv row processed in two 28-wide halves
// (seg[35] not seg[62]) to cut peak VGPR ~130 -> ~100. Target 4 blocks/CU
// (was 2). Conv accumulation order per element unchanged -> bit-identical.
// XCD swizzle kept (measured -36 us in r4).
__global__ __launch_bounds__(256) void convln_kernel(
    const float* __restrict__ x, const float* __restrict__ cw,
    const float* __restrict__ cb, const float* __restrict__ lng,
    const float* __restrict__ lnb, unsigned short* __restrict__ y){
  __shared__ float tile[256 * 15];     // [c][14 pos + 1 pad]
  __shared__ float part_s[16][16];
  __shared__ float part_q[16][16];
  __shared__ float lg_s[256];
  __shared__ float lb_s[256];

  const int t = threadIdx.x;
  const int blk0 = blockIdx.x;
  const int blk = (blk0 & 7) * 224 + (blk0 >> 3);   // XCD-contiguous logical id
  const int b = blk / 56;
  const int h = blk - b * 56;
  const int c = t;

  lg_s[t] = lng[t];
  lb_s[t] = lnb[t];

  float acc[56];
  {
    float bias = cb[c];
    #pragma unroll
    for (int w = 0; w < 56; ++w) acc[w] = bias;
  }

  const float* xim = x + (long)(b * 256 + c) * HW;
  const float* cwc = cw + c * 49;
  for (int i = 0; i < 7; ++i){
    int hh = h - 3 + i;
    if (hh >= 0 && hh < 56){                    // uniform per block
      const float* xrow = xim + hh * 56;
      float wt7[7];
      #pragma unroll
      for (int j = 0; j < 7; ++j) wt7[j] = cwc[i * 7 + j];

      // half A: outputs w 0..27, needs x[-3..30] -> sa[i]=x[i-3]
      {
        float sa[35];
        sa[0] = sa[1] = sa[2] = 0.f;
        #pragma unroll
        for (int v4 = 0; v4 < 8; ++v4){
          f32x4 v = *(const f32x4*)(xrow + v4 * 4);
          sa[3 + v4 * 4 + 0] = v[0];
          sa[3 + v4 * 4 + 1] = v[1];
          sa[3 + v4 * 4 + 2] = v[2];
          sa[3 + v4 * 4 + 3] = v[3];
        }
        #pragma unroll
        for (int j = 0; j < 7; ++j){
          float wj = wt7[j];
          #pragma unroll
          for (int w = 0; w < 28; ++w)
            acc[w] = fmaf(sa[w + j], wj, acc[w]);
        }
      }
      // half B: outputs w 28..55, needs x[25..58] -> sb[i]=x[24+i]
      {
        float sb[35];
        sb[32] = sb[33] = sb[34] = 0.f;
        #pragma unroll
        for (int v4 = 0; v4 < 8; ++v4){
          f32x4 v = *(const f32x4*)(xrow + 24 + v4 * 4);
          sb[v4 * 4 + 0] = v[0];
          sb[v4 * 4 + 1] = v[1];
          sb[v4 * 4 + 2] = v[2];
          sb[v4 * 4 + 3] = v[3];
        }
        #pragma unroll
        for (int j = 0; j < 7; ++j){
          float wj = wt7[j];
          #pragma unroll
          for (int w = 28; w < 56; ++w)
            acc[w] = fmaf(sb[w + j - 27], wj, acc[w]);
        }
      }
    }
  }

  // LayerNorm in 4 chunks of 14 positions (tile = [256 c][15])
  for (int ck = 0; ck < 4; ++ck){
    const int p0 = ck * 14;
    __syncthreads();                    // previous chunk's tile readers done
    #pragma unroll
    for (int dp = 0; dp < 14; ++dp) tile[c * 15 + dp] = acc[p0 + dp];
    __syncthreads();

    // per-position partial sums: 16 c-groups x 14 positions
    {
      const int dp = t & 15, cg = t >> 4;
      if (dp < 14){
        float s = 0.f, q = 0.f;
        #pragma unroll
        for (int j = 0; j < 16; ++j){
          float v = tile[(cg * 16 + j) * 15 + dp];
          s += v; q = fmaf(v, v, q);
        }
        part_s[cg][dp] = s;
        part_q[cg][dp] = q;
      }
    }
    __syncthreads();

    // normalize + affine + bf16, swizzled y write (slot j stored at j^(pos&7))
    if (t < 224){
      const int pp = t >> 4;            // 0..13
      const int cs = t & 15;
      float S = 0.f, Q = 0.f;
      #pragma unroll
      for (int g = 0; g < 16; ++g){ S += part_s[g][pp]; Q += part_q[g][pp]; }
      float mu = S * (1.0f / 256.0f);
      float var = Q * (1.0f / 256.0f) - mu * mu;
      float rs = rsqrtf(var + 1e-6f);
      long pos = (long)blk * 56 + p0 + pp;
      int m7 = (int)(pos & 7);
      int c0 = cs * 16;
      bf16x8 o0, o1;
      #pragma unroll
      for (int k = 0; k < 8; ++k){
        float v0 = tile[(c0 + k) * 15 + pp];
        float v1 = tile[(c0 + 8 + k) * 15 + pp];
        o0[k] = (short)f2bf((v0 - mu) * rs * lg_s[c0 + k] + lb_s[c0 + k]);
        o1[k] = (short)f2bf((v1 - mu) * rs * lg_s[c0 + 8 + k] + lb_s[c0 + 8 + k]);
      }
      unsigned short* yp = y + pos * 256;
      int j0 = cs * 2;
      *(bf16x8*)(yp + ((j0 ^ m7) << 3)) = o0;
      *(bf16x8*)(yp + (((j0 + 1) ^ m7) << 3)) = o1;
    }
  }
}

// ---------------- fused MLP, BM=64, 256 thr (round-4 version, unchanged)
#define LDS_H0 32768
#define MLP_LDS (32768 + 18432)

__global__ __launch_bounds__(256, 3) void mlp_kernel(
    const unsigned short* __restrict__ y, const unsigned short* __restrict__ w1t,
    const unsigned short* __restrict__ w2t, const float* __restrict__ b1,
    const float* __restrict__ b2, float* __restrict__ out){
  __shared__ __align__(16) unsigned char smem[MLP_LDS];
  const int t = threadIdx.x;
  const int wv = t >> 6, lane = t & 63;
  const int lr = lane & 15, lq = lane >> 4;
  const int r7 = lr & 7;
  const int blk = blockIdx.x;

  // stage y tile: 64 rows x 512B, linear (32 groups x 1024B)
  {
    const unsigned char* ybase = (const unsigned char*)(y + (long)blk * 64 * 256);
    #pragma unroll
    for (int r = 0; r < 8; ++r){
      int g = wv * 8 + r;
      load_lds16(ybase + g * 1024 + lane * 16, smem + g * 1024);
    }
  }

  // prologue: wf for chunk 0 (overlaps the staging drain)
  bf16x8 wf[8];
  {
    const unsigned short* w1p = w1t + ((wv * 16 + lr) << 8);
    #pragma unroll
    for (int ks = 0; ks < 8; ++ks)
      wf[ks] = *(const bf16x8*)(w1p + ks * 32 + lq * 8);
  }

  f32x4 acc2[4][4];
  #pragma unroll
  for (int a = 0; a < 4; ++a)
    #pragma unroll
    for (int bb = 0; bb < 4; ++bb) acc2[a][bb] = (f32x4){0.f, 0.f, 0.f, 0.f};

  __syncthreads();   // staging barrier (must drain global_load_lds -> vmcnt)

  for (int ch = 0; ch < 16; ++ch){
    unsigned char* Hbuf = smem + LDS_H0 + (ch & 1) * 9216;

    // phase 1: P^T[f][m] = w1 . y^T  (wf was prefetched last iteration)
    f32x4 acc1[4];
    #pragma unroll
    for (int mt = 0; mt < 4; ++mt) acc1[mt] = (f32x4){0.f, 0.f, 0.f, 0.f};
    #pragma unroll
    for (int ks = 0; ks < 8; ++ks){
      bf16x8 yf[4];
      #pragma unroll
      for (int mt = 0; mt < 4; ++mt){
        int jl = ks * 4 + lq;
        int ofs = (mt * 16 + lr) * 512 + (((jl & 24) | ((jl ^ r7) & 7)) << 4);
        yf[mt] = *(const bf16x8*)(smem + ofs);
      }
      #pragma unroll
      for (int mt = 0; mt < 4; ++mt)
        acc1[mt] = __builtin_amdgcn_mfma_f32_16x16x32_bf16(wf[ks], yf[mt], acc1[mt], 0, 0, 0);
    }

    // issue w2f now: in flight across GELU + barrier
    bf16x8 w2f[2][4];
    #pragma unroll
    for (int ks2 = 0; ks2 < 2; ++ks2)
      #pragma unroll
      for (int ct = 0; ct < 4; ++ct)
        w2f[ks2][ct] = *(const bf16x8*)(w2t + (long)(wv * 64 + ct * 16 + lr) * 1024
                                        + ch * 64 + ks2 * 32 + lq * 8);

    // bias + tanh-GELU -> H[m][f_in_chunk]
    {
      f32x4 bv = *(const f32x4*)(b1 + ch * 64 + wv * 16 + lq * 4);
      #pragma unroll
      for (int mt = 0; mt < 4; ++mt){
        bf16x4 hv;
        #pragma unroll
        for (int r = 0; r < 4; ++r){
          float pv = acc1[mt][r] + bv[r];
          float p2 = pv * pv;
          float u  = pv * fmaf(0.044715f, p2, 1.0f);
          float e  = __builtin_amdgcn_exp2f(-2.3022083f * u);
          float gl = pv * __builtin_amdgcn_rcpf(1.0f + e);
          hv[r] = (short)f2bf(gl);
        }
        *(bf16x4*)(Hbuf + (mt * 16 + lr) * 144 + wv * 32 + lq * 8) = hv;
      }
    }

    // prefetch wf for next chunk (in flight across barrier + phase 2)
    {
      int chn = (ch + 1) & 15;
      const unsigned short* w1p = w1t + (((chn * 64) + wv * 16 + lr) << 8);
      #pragma unroll
      for (int ks = 0; ks < 8; ++ks)
        wf[ks] = *(const bf16x8*)(w1p + ks * 32 + lq * 8);
    }

    // chunk barrier: drain DS only (H writes visible); NO vmcnt drain.
    asm volatile("s_waitcnt lgkmcnt(0)" ::: "memory");
    __builtin_amdgcn_sched_barrier(0);
    __builtin_amdgcn_s_barrier();

    // phase 2: acc2[c][m] += w2[c][f] . h[m][f]
    #pragma unroll
    for (int ks2 = 0; ks2 < 2; ++ks2){
      bf16x8 hf[4];
      #pragma unroll
      for (int mt = 0; mt < 4; ++mt)
        hf[mt] = *(const bf16x8*)(Hbuf + (mt * 16 + lr) * 144 + ks2 * 64 + lq * 16);
      #pragma unroll
      for (int ct = 0; ct < 4; ++ct)
        #pragma unroll
        for (int mt = 0; mt < 4; ++mt)
          acc2[ct][mt] = __builtin_amdgcn_mfma_f32_16x16x32_bf16(w2f[ks2][ct], hf[mt], acc2[ct][mt], 0, 0, 0);
    }
  }

  // epilogue: + b2, NCHW fp32 stores (16 m-consecutive lanes = 64B lines)
  #pragma unroll
  for (int ct = 0; ct < 4; ++ct){
    int cb = wv * 64 + ct * 16 + lq * 4;
    f32x4 b2v = *(const f32x4*)(b2 + cb);
    #pragma unroll
    for (int mt = 0; mt < 4; ++mt){
      int m = mt * 16 + lr;
      unsigned pos = (unsigned)(blk * 64 + m);
      unsigned bimg = pos / 3136u;
      unsigned hw = pos - bimg * 3136u;
      float* op = out + ((long)bimg * 256 + cb) * 3136 + hw;
      #pragma unroll
      for (int r = 0; r < 4; ++r)
        op[r * 3136] = acc2[ct][mt][r] + b2v[r];
    }
  }
}

extern "C" void kernel_launch(void* const* d_in, const int* in_sizes, int n_in,
                              void* d_out, int out_size, void* d_ws, size_t ws_size,
                              hipStream_t stream){
  const float* x  = (const float*)d_in[0];
  const float* cw = (const float*)d_in[1];
  const float* cb = (const float*)d_in[2];
  const float* lg = (const float*)d_in[3];
  const float* lb = (const float*)d_in[4];
  const float* w1 = (const float*)d_in[5];
  const float* b1 = (const float*)d_in[6];
  const float* w2 = (const float*)d_in[7];
  const float* b2 = (const float*)d_in[8];
  float* out = (float*)d_out;

  // workspace: y (51,380,224 B) | w1t (524,288 B) | w2t (524,288 B)
  unsigned short* y   = (unsigned short*)d_ws;
  unsigned short* w1t = (unsigned short*)((char*)d_ws + 51380224);
  unsigned short* w2t = (unsigned short*)((char*)d_ws + 51904512);

  hipLaunchKernelGGL(prep_kernel,   dim3(128),  dim3(256), 0, stream, w1, w2, w1t, w2t);
  hipLaunchKernelGGL(convln_kernel, dim3(1792), dim3(256), 0, stream, x, cw, cb, lg, lb, y);
  hipLaunchKernelGGL(mlp_kernel,    dim3(1568), dim3(256), 0, stream, y, w1t, w2t, b1, b2, out);
}